// Round 3
// baseline (16184.232 us; speedup 1.0000x reference)
//
#include <hip/hip_runtime.h>

typedef unsigned short u16;
typedef short s8v __attribute__((ext_vector_type(8)));   // 8 x bf16
typedef float f4v __attribute__((ext_vector_type(4)));

#define B_ 256
#define T_ 64
#define I_ 512
#define H_ 1024
#define O_ 2

#define SPK0_OFF ((size_t)0)
#define SPK1_OFF ((size_t)T_*B_*H_)                  // 16777216
#define SPK2_OFF ((size_t)2*T_*B_*H_)                // 33554432
#define MEM0_OFF ((size_t)2*T_*B_*H_ + (size_t)T_*B_*O_)
#define MEM1_OFF (MEM0_OFF + (size_t)T_*B_*H_)
#define MEM2_OFF (MEM1_OFF + (size_t)T_*B_*H_)

// d_ws layout (floats): [0] = dtype flag (int), [1024..) mem0 state [B*H],
// then mem1 state [B*H], then mem2 state [B*O]. All fp32.
#define WS_MEM0 1024
#define WS_MEM1 (1024 + B_*H_)
#define WS_MEM2 (1024 + 2*B_*H_)
#define WS_TOTAL (1024 + 2*B_*H_ + B_*O_)

__device__ __forceinline__ float b2f(u16 u) {
    return __uint_as_float(((unsigned)u) << 16);
}
__device__ __forceinline__ u16 f2b(float f) {  // RNE
    unsigned u = __float_as_uint(f);
    return (u16)((u + 0x7FFFu + ((u >> 16) & 1u)) >> 16);
}

__device__ __forceinline__ float dot_bf(const u16* a, const u16* b, int K) {
    float acc = 0.0f;
    for (int k = 0; k < K; k += 8) {
        s8v av = *(const s8v*)(a + k);
        s8v bv = *(const s8v*)(b + k);
        #pragma unroll
        for (int j = 0; j < 8; ++j)
            acc += b2f((u16)av[j]) * b2f((u16)bv[j]);
    }
    return acc;
}
__device__ __forceinline__ float dot_f32(const float* a, const float* b, int K) {
    float acc = 0.0f;
    for (int k = 0; k < K; k += 8) {
        f4v a0 = *(const f4v*)(a + k);
        f4v a1 = *(const f4v*)(a + k + 4);
        f4v b0 = *(const f4v*)(b + k);
        f4v b1 = *(const f4v*)(b + k + 4);
        #pragma unroll
        for (int j = 0; j < 4; ++j) acc += a0[j]*b0[j];
        #pragma unroll
        for (int j = 0; j < 4; ++j) acc += a1[j]*b1[j];
    }
    return acc;
}
__device__ __forceinline__ bool step_active(const int* nsp, int t) {
    int ns = *nsp;                       // hedge: only trust sane values
    return !(ns >= 1 && ns <= T_ && t >= ns);
}

__global__ __launch_bounds__(256) void k_zero(float* p, int n) {
    int i = blockIdx.x * 256 + threadIdx.x;
    if (i < n) p[i] = 0.0f;
}

// x is binary 0/1. fp32 words are only {0, 0x3F800000}; bf16-pair words hit
// low16 == 0x3F80 (element at even index == 1.0) with P~0.2/word.
__global__ void k_detect(const unsigned* __restrict__ xw, int* __restrict__ flag) {
    unsigned v = xw[threadIdx.x];        // 64 words = 128 bf16 or 64 fp32
    unsigned long long m = __ballot((v & 0xFFFFu) == 0x3F80u);
    if (threadIdx.x == 0) *flag = (m != 0ull) ? 1 : 0;
}

// Layers 0/1: one thread per (b,h) output. block=256: 32 b x 8 h.
__global__ __launch_bounds__(256) void k_l0(
    const void* __restrict__ x, const void* __restrict__ W0,
    const void* __restrict__ thrp, void* __restrict__ out,
    float* __restrict__ ms, const int* __restrict__ flag,
    const int* __restrict__ nsp, int t)
{
    if (!step_active(nsp, t)) return;
    const int isbf = *flag;
    const int b = blockIdx.y * 32 + (threadIdx.x & 31);
    const int h = blockIdx.x * 8 + (threadIdx.x >> 5);
    float thr, cur;
    if (isbf) {
        thr = b2f(((const u16*)thrp)[0]);
        cur = dot_bf((const u16*)x + (size_t)(b*T_ + t)*I_,
                     (const u16*)W0 + (size_t)h*I_, I_);
    } else {
        thr = ((const float*)thrp)[0];
        cur = dot_f32((const float*)x + (size_t)(b*T_ + t)*I_,
                      (const float*)W0 + (size_t)h*I_, I_);
    }
    float* msp = ms + b*H_ + h;
    float mp = *msp;
    float m = 0.5f*mp + cur - ((mp > thr) ? thr : 0.0f);
    float sp = ((m - thr) > 0.0f) ? 1.0f : 0.0f;
    *msp = m;
    size_t oi = (size_t)t*B_*H_ + (size_t)b*H_ + h;
    if (isbf) {
        ((u16*)out)[SPK0_OFF + oi] = f2b(sp);
        ((u16*)out)[MEM0_OFF + oi] = f2b(m);
    } else {
        ((float*)out)[SPK0_OFF + oi] = sp;
        ((float*)out)[MEM0_OFF + oi] = m;
    }
}

__global__ __launch_bounds__(256) void k_l1(
    const void* __restrict__ W1, const void* __restrict__ thrp,
    void* __restrict__ out, float* __restrict__ ms,
    const int* __restrict__ flag, const int* __restrict__ nsp, int t)
{
    if (!step_active(nsp, t)) return;
    const int isbf = *flag;
    const int b = blockIdx.y * 32 + (threadIdx.x & 31);
    const int h = blockIdx.x * 8 + (threadIdx.x >> 5);
    float thr, cur;
    size_t in_row = SPK0_OFF + (size_t)t*B_*H_ + (size_t)b*H_;
    if (isbf) {
        thr = b2f(((const u16*)thrp)[0]);
        cur = dot_bf((const u16*)out + in_row, (const u16*)W1 + (size_t)h*H_, H_);
    } else {
        thr = ((const float*)thrp)[0];
        cur = dot_f32((const float*)out + in_row, (const float*)W1 + (size_t)h*H_, H_);
    }
    float* msp = ms + b*H_ + h;
    float mp = *msp;
    float m = 0.5f*mp + cur - ((mp > thr) ? thr : 0.0f);
    float sp = ((m - thr) > 0.0f) ? 1.0f : 0.0f;
    *msp = m;
    size_t oi = (size_t)t*B_*H_ + (size_t)b*H_ + h;
    if (isbf) {
        ((u16*)out)[SPK1_OFF + oi] = f2b(sp);
        ((u16*)out)[MEM1_OFF + oi] = f2b(m);
    } else {
        ((float*)out)[SPK1_OFF + oi] = sp;
        ((float*)out)[MEM1_OFF + oi] = m;
    }
}

// Layer 2: 2 blocks x 256 threads; thread = one (b,o), full-K dot.
__global__ __launch_bounds__(256) void k_l2(
    const void* __restrict__ W2, const void* __restrict__ thrp,
    void* __restrict__ out, float* __restrict__ ms,
    const int* __restrict__ flag, const int* __restrict__ nsp, int t)
{
    if (!step_active(nsp, t)) return;
    const int isbf = *flag;
    const int b = blockIdx.x * 128 + (threadIdx.x >> 1);
    const int o = threadIdx.x & 1;
    float thr, cur;
    size_t in_row = SPK1_OFF + (size_t)t*B_*H_ + (size_t)b*H_;
    if (isbf) {
        thr = b2f(((const u16*)thrp)[0]);
        cur = dot_bf((const u16*)out + in_row, (const u16*)W2 + (size_t)o*H_, H_);
    } else {
        thr = ((const float*)thrp)[0];
        cur = dot_f32((const float*)out + in_row, (const float*)W2 + (size_t)o*H_, H_);
    }
    float* msp = ms + b*O_ + o;
    float mp = *msp;
    float m = 0.5f*mp + cur - ((mp > thr) ? thr : 0.0f);
    float sp = ((m - thr) > 0.0f) ? 1.0f : 0.0f;
    *msp = m;
    size_t oi = (size_t)t*B_*O_ + (size_t)b*O_ + o;
    if (isbf) {
        ((u16*)out)[SPK2_OFF + oi] = f2b(sp);
        ((u16*)out)[MEM2_OFF + oi] = f2b(m);
    } else {
        ((float*)out)[SPK2_OFF + oi] = sp;
        ((float*)out)[MEM2_OFF + oi] = m;
    }
}

extern "C" void kernel_launch(void* const* d_in, const int* in_sizes, int n_in,
                              void* d_out, int out_size, void* d_ws, size_t ws_size,
                              hipStream_t stream) {
    const void* x  = d_in[0];
    const void* W0 = d_in[1];
    const void* W1 = d_in[2];
    const void* W2 = d_in[3];
    const void* t0 = d_in[4];
    const void* t1 = d_in[5];
    const void* t2 = d_in[6];
    const int*  ns = (const int*)d_in[7];

    float* wsf  = (float*)d_ws;
    int*   flag = (int*)d_ws;
    float* mem0 = wsf + WS_MEM0;
    float* mem1 = wsf + WS_MEM1;
    float* mem2 = wsf + WS_MEM2;

    // d_ws is re-poisoned 0xAA each launch: zero state + flag via kernel.
    hipLaunchKernelGGL(k_zero, dim3((WS_TOTAL + 255) / 256), dim3(256), 0, stream,
                       wsf, WS_TOTAL);
    hipLaunchKernelGGL(k_detect, dim3(1), dim3(64), 0, stream,
                       (const unsigned*)x, flag);

    for (int t = 0; t < T_; ++t) {
        hipLaunchKernelGGL(k_l0, dim3(H_/8, B_/32), dim3(256), 0, stream,
                           x, W0, t0, d_out, mem0, flag, ns, t);
        hipLaunchKernelGGL(k_l1, dim3(H_/8, B_/32), dim3(256), 0, stream,
                           W1, t1, d_out, mem1, flag, ns, t);
        hipLaunchKernelGGL(k_l2, dim3(2), dim3(256), 0, stream,
                           W2, t2, d_out, mem2, flag, ns, t);
    }
}